// Round 1
// baseline (2293.652 us; speedup 1.0000x reference)
//
#include <hip/hip_runtime.h>
#include <hip/hip_bf16.h>

typedef float f32x4 __attribute__((ext_vector_type(4)));
typedef __bf16 bf16x8 __attribute__((ext_vector_type(8)));

#define AS1 __attribute__((address_space(1)))
#define AS3 __attribute__((address_space(3)))

__device__ __forceinline__ void gload16(const void* g, void* l) {
    __builtin_amdgcn_global_load_lds((AS1 unsigned int*)g, (AS3 unsigned int*)l, 16, 0, 0);
}

// ---------------- weight prep: OIHW f32 -> [kyx][icg][nblk][oc128][ic32] bf16 ----------------
__global__ __launch_bounds__(256) void prep_w_kernel(const float* __restrict__ w,
                                                     __hip_bfloat16* __restrict__ wp) {
    // grid 512: bid = nblk*256 + oc4*8 + icg
    __shared__ float wl[4 * 32 * 81];  // [o][i][kyx]
    int bid = blockIdx.x;
    int icg = bid & 7;
    int oc4 = (bid >> 3) & 31;
    int nblk = bid >> 8;
    int t = threadIdx.x;
    int ocg0 = nblk * 128 + oc4 * 4;
    int ic0 = icg * 32;
    for (int f = t; f < 4 * 2592; f += 256) {
        int o = f / 2592;
        int rest = f - o * 2592;  // i*81 + kyx
        wl[f] = w[(ocg0 + o) * 20736 + ic0 * 81 + rest];
    }
    __syncthreads();
    for (int idx = t; idx < 81 * 128; idx += 256) {
        int kyx = idx >> 7;
        int o = (idx >> 5) & 3;
        int i = idx & 31;
        long dst = (long)(((kyx * 8 + icg) * 2 + nblk) * 128 + (oc4 * 4 + o)) * 32 + i;
        wp[dst] = __float2bfloat16(wl[o * 2592 + i * 81 + kyx]);
    }
}

// ---------------- conv1: 1->256ch 9x9 s1, f32 compute, NHWC bf16 out + relu ----------------
__global__ __launch_bounds__(256) void conv1_kernel(const float* __restrict__ x,
                                                    const float* __restrict__ w,
                                                    const float* __restrict__ bias,
                                                    __hip_bfloat16* __restrict__ out) {
    __shared__ float rowb[504];  // 9 rows x 56
    int oy = blockIdx.x;  // 0..47
    int b = blockIdx.y;   // 0..127
    int t = threadIdx.x;  // = oc
    const float* src = x + b * 3136 + oy * 56;
    for (int i = t; i < 504; i += 256) rowb[i] = src[i];
    __syncthreads();
    const float* wp = w + t * 81;
    float acc[48];
#pragma unroll
    for (int i = 0; i < 48; ++i) acc[i] = 0.f;
    for (int ky = 0; ky < 9; ++ky) {
        float r[56];
#pragma unroll
        for (int i = 0; i < 56; ++i) r[i] = rowb[ky * 56 + i];
#pragma unroll
        for (int kx = 0; kx < 9; ++kx) {
            float wv = wp[ky * 9 + kx];
#pragma unroll
            for (int ox = 0; ox < 48; ++ox) acc[ox] = fmaf(wv, r[ox + kx], acc[ox]);
        }
    }
    float bs = bias[t];
    __hip_bfloat16* op = out + ((b * 48 + oy) * 48) * 256 + t;
#pragma unroll
    for (int ox = 0; ox < 48; ++ox) {
        float v = acc[ox] + bs;
        v = v > 0.f ? v : 0.f;
        op[ox * 256] = __float2bfloat16(v);
    }
}

// ---------------- implicit-GEMM conv (bf16 MFMA), NHWC in/out, relu ----------------
// C[M=B*HWout][256] = im2col(in) x wp ; K-order = (ky,kx) major, ic minor.
__global__ __launch_bounds__(256) void conv_mfma_kernel(const __hip_bfloat16* __restrict__ in,
                                                        const __hip_bfloat16* __restrict__ wp,
                                                        const float* __restrict__ bias,
                                                        __hip_bfloat16* __restrict__ out,
                                                        int Win, int imgStride, int HWout, int Wout) {
    __shared__ __hip_bfloat16 Ald[4096];  // [row128][k32]
    __shared__ __hip_bfloat16 Bld[4096];  // [oc128][k32]
    int mblk = blockIdx.x, nblk = blockIdx.y;
    int t = threadIdx.x;
    int lane = t & 63, wid = t >> 6;
    int icq8 = (t & 3) * 8;

    long base0, base1;
    {
        int m = mblk * 128 + (t >> 2);
        int b = m / HWout; int rem = m - b * HWout;
        int oyy = rem / Wout; int oxx = rem - oyy * Wout;
        base0 = (long)b * imgStride + (long)(2 * oyy * Win + 2 * oxx) * 256;
        m += 64;
        b = m / HWout; rem = m - b * HWout;
        oyy = rem / Wout; oxx = rem - oyy * Wout;
        base1 = (long)b * imgStride + (long)(2 * oyy * Win + 2 * oxx) * 256;
    }
    char* ldsA0 = (char*)Ald + wid * 1024;
    char* ldsA1 = (char*)Ald + 4096 + wid * 1024;
    char* ldsB0 = (char*)Bld + wid * 1024;
    char* ldsB1 = (char*)Bld + 4096 + wid * 1024;

    f32x4 acc[4][4];
#pragma unroll
    for (int i = 0; i < 4; ++i)
#pragma unroll
        for (int j2 = 0; j2 < 4; ++j2) acc[i][j2] = (f32x4){0.f, 0.f, 0.f, 0.f};

    int wr = wid >> 1, wc = wid & 1;
    int arow_off = (wr * 64 + (lane & 15)) * 32 + (lane >> 4) * 8;  // elems
    int brow_off = (wc * 64 + (lane & 15)) * 32 + (lane >> 4) * 8;

    for (int s = 0; s < 648; ++s) {
        int kyx = s >> 3, icg = s & 7;
        int ky = kyx / 9, kx = kyx - ky * 9;
        long offA = (long)(ky * Win + kx) * 256 + icg * 32 + icq8;
        long btb = (long)((kyx * 8 + icg) * 2 + nblk) * 4096;
        __syncthreads();
        gload16(in + base0 + offA, ldsA0);
        gload16(in + base1 + offA, ldsA1);
        gload16(wp + btb + t * 8, ldsB0);
        gload16(wp + btb + (t + 256) * 8, ldsB1);
        __syncthreads();
        bf16x8 af[4], bfr[4];
#pragma unroll
        for (int i = 0; i < 4; ++i) af[i] = *(const bf16x8*)(Ald + arow_off + i * 512);
#pragma unroll
        for (int i = 0; i < 4; ++i) bfr[i] = *(const bf16x8*)(Bld + brow_off + i * 512);
#pragma unroll
        for (int mi = 0; mi < 4; ++mi)
#pragma unroll
            for (int ni = 0; ni < 4; ++ni)
                acc[mi][ni] = __builtin_amdgcn_mfma_f32_16x16x32_bf16(af[mi], bfr[ni], acc[mi][ni], 0, 0, 0);
    }
    int colbase = nblk * 128 + wc * 64 + (lane & 15);
    long mrowbase = (long)mblk * 128 + wr * 64 + (lane >> 4) * 4;
#pragma unroll
    for (int mi = 0; mi < 4; ++mi) {
#pragma unroll
        for (int ni = 0; ni < 4; ++ni) {
            int col = colbase + ni * 16;
            float bs = bias[col];
#pragma unroll
            for (int r = 0; r < 4; ++r) {
                long mrow = mrowbase + mi * 16 + r;
                float v = acc[mi][ni][r] + bs;
                v = v > 0.f ? v : 0.f;
                out[mrow * 256 + col] = __float2bfloat16(v);
            }
        }
    }
}

// ---------------- primary capsule squash: NHWC bf16 -> u f32 [B,1152,8] ----------------
__global__ __launch_bounds__(256) void squash_caps_kernel(const __hip_bfloat16* __restrict__ c3,
                                                          float* __restrict__ u) {
    int g = blockIdx.x * 256 + threadIdx.x;  // 147456 = 128*1152
    int b = g / 1152, i = g - b * 1152;
    float val[8];
    float sn = 0.f;
#pragma unroll
    for (int d = 0; d < 8; ++d) {
        int flat = i * 8 + d;
        int c = flat / 36; int rem = flat - c * 36;
        int y = rem / 6; int xx = rem - y * 6;
        float vv = __bfloat162float(c3[((b * 6 + y) * 6 + xx) * 256 + c]);
        val[d] = vv;
        sn += vv * vv;
    }
    float sc = (sn / (1.f + sn)) / sqrtf(sn + 1e-8f);
#pragma unroll
    for (int d = 0; d < 8; ++d) u[(long)g * 8 + d] = val[d] * sc;
}

// ---------------- u_hat[b,j,i,o] = sum_d u[b,i,d] * W[j,i,d,o]  (bf16 out, [b][j][i][o]) ----------------
__global__ __launch_bounds__(256) void uhat_kernel(const float* __restrict__ u,
                                                   const float* __restrict__ Wd,
                                                   __hip_bfloat16* __restrict__ uhat) {
    __shared__ float Wl[1280];  // [j][d][o]
    __shared__ float ul[1024];  // [b][d]
    int i = blockIdx.x, t = threadIdx.x;
    for (int idx = t; idx < 1280; idx += 256) {
        int j = idx >> 7, rest = idx & 127;
        Wl[idx] = Wd[((long)j * 1152 + i) * 128 + rest];
    }
    for (int idx = t; idx < 1024; idx += 256) {
        int b = idx >> 3, d = idx & 7;
        ul[idx] = u[((long)b * 1152 + i) * 8 + d];
    }
    __syncthreads();
    for (int rr = 0; rr < 80; ++rr) {
        int idx = rr * 256 + t;
        int b = idx / 160; int jo = idx - b * 160;
        int j = jo >> 4, o = jo & 15;
        float a = 0.f;
#pragma unroll
        for (int d = 0; d < 8; ++d) a += ul[b * 8 + d] * Wl[j * 128 + d * 16 + o];
        uhat[(((long)b * 10 + j) * 1152 + i) * 16 + o] = __float2bfloat16(a);
    }
}

// ---------------- fused dynamic routing per (b,j): 3 iterations in LDS ----------------
__global__ __launch_bounds__(256) void routing_kernel(const __hip_bfloat16* __restrict__ uhat,
                                                      const float* __restrict__ bdig,
                                                      float* __restrict__ vout,
                                                      float* __restrict__ vws) {
    __shared__ __hip_bfloat16 uh[1152 * 16];
    __shared__ float barr[1152];
    __shared__ float red[256];
    __shared__ float accb[16 * 256];
    __shared__ float svec[16];
    int bid = blockIdx.x;  // b*10 + j
    int j = bid % 10;
    int t = threadIdx.x;
    const uint4* srcp = (const uint4*)(uhat + (long)bid * 18432);
    uint4* dstp = (uint4*)uh;
    for (int idx = t; idx < 2304; idx += 256) dstp[idx] = srcp[idx];
    for (int idx = t; idx < 1152; idx += 256) barr[idx] = 0.f;
    __syncthreads();
    for (int it = 0; it < 3; ++it) {
        float lm = -1e30f;
        for (int i = t; i < 1152; i += 256) lm = fmaxf(lm, barr[i]);
        red[t] = lm;
        __syncthreads();
        for (int s2 = 128; s2 > 0; s2 >>= 1) {
            if (t < s2) red[t] = fmaxf(red[t], red[t + s2]);
            __syncthreads();
        }
        float mx = red[0];
        __syncthreads();
        float le = 0.f;
        float a16[16];
#pragma unroll
        for (int o = 0; o < 16; ++o) a16[o] = 0.f;
        for (int i = t; i < 1152; i += 256) {
            float e = __expf(barr[i] - mx);
            le += e;
            const __hip_bfloat16* up = uh + i * 16;
#pragma unroll
            for (int o = 0; o < 16; ++o) a16[o] += e * __bfloat162float(up[o]);
        }
        red[t] = le;
        __syncthreads();
        for (int s2 = 128; s2 > 0; s2 >>= 1) {
            if (t < s2) red[t] += red[t + s2];
            __syncthreads();
        }
        float sume = red[0];
        __syncthreads();
#pragma unroll
        for (int o = 0; o < 16; ++o) accb[o * 256 + t] = a16[o];
        __syncthreads();
        if (t < 16) {
            float s = 0.f;
            for (int q = 0; q < 256; ++q) s += accb[t * 256 + q];
            svec[t] = s / sume + bdig[j * 16 + t];
        }
        __syncthreads();
        if (t == 0) {
            float sn = 0.f;
#pragma unroll
            for (int o = 0; o < 16; ++o) sn += svec[o] * svec[o];
            red[0] = (sn / (1.f + sn)) / sqrtf(sn + 1e-8f);
        }
        __syncthreads();
        float sc = red[0];
        if (it < 2) {
            float vv[16];
#pragma unroll
            for (int o = 0; o < 16; ++o) vv[o] = svec[o] * sc;
            for (int i = t; i < 1152; i += 256) {
                const __hip_bfloat16* up = uh + i * 16;
                float dot = 0.f;
#pragma unroll
                for (int o = 0; o < 16; ++o) dot += vv[o] * __bfloat162float(up[o]);
                barr[i] += dot;
            }
            __syncthreads();
        } else {
            if (t < 16) {
                float v = svec[t] * sc;
                vout[bid * 16 + t] = v;
                vws[bid * 16 + t] = v;
            }
        }
    }
}

// ---------------- reconstruction GEMM: out[128,N] = act(A[128,K] x W[K,N] + bias) ----------------
__global__ __launch_bounds__(256) void rec_gemm_kernel(const float* __restrict__ A,
                                                       const float* __restrict__ W,
                                                       const float* __restrict__ bias,
                                                       float* __restrict__ out,
                                                       int K, int N, int act) {
    __shared__ float As[32 * 64];
    int n0 = blockIdx.x * 64;
    int bch = blockIdx.y * 32;
    int t = threadIdx.x;
    int n_l = t & 63, bh = t >> 6;
    float acc[8];
#pragma unroll
    for (int i = 0; i < 8; ++i) acc[i] = 0.f;
    for (int k0 = 0; k0 < K; k0 += 64) {
        int kc = K - k0;
        if (kc > 64) kc = 64;
        __syncthreads();
        for (int idx = t; idx < 2048; idx += 256) {
            int bb = idx >> 6, kk = idx & 63;
            if (kk < kc) As[idx] = A[(long)(bch + bb) * K + k0 + kk];
        }
        __syncthreads();
        for (int kk = 0; kk < kc; ++kk) {
            float wv = W[(long)(k0 + kk) * N + n0 + n_l];
#pragma unroll
            for (int bb = 0; bb < 8; ++bb) acc[bb] += As[(bh * 8 + bb) * 64 + kk] * wv;
        }
    }
    float bs = bias[n0 + n_l];
    for (int bb = 0; bb < 8; ++bb) {
        float x = acc[bb] + bs;
        float r;
        if (act == 0) r = x > 0.f ? x : 0.f;
        else r = 1.f / (1.f + __expf(-x));
        out[(long)(bch + bh * 8 + bb) * N + n0 + n_l] = r;
    }
}

extern "C" void kernel_launch(void* const* d_in, const int* in_sizes, int n_in,
                              void* d_out, int out_size, void* d_ws, size_t ws_size,
                              hipStream_t stream) {
    const float* x   = (const float*)d_in[0];
    const float* c1w = (const float*)d_in[1];
    const float* c1b = (const float*)d_in[2];
    const float* c2w = (const float*)d_in[3];
    const float* c2b = (const float*)d_in[4];
    const float* pw  = (const float*)d_in[5];
    const float* pb  = (const float*)d_in[6];
    const float* Wd  = (const float*)d_in[7];
    const float* bd  = (const float*)d_in[8];
    const float* rw1 = (const float*)d_in[9];
    const float* rb1 = (const float*)d_in[10];
    const float* rw2 = (const float*)d_in[11];
    const float* rb2 = (const float*)d_in[12];
    const float* rw3 = (const float*)d_in[13];
    const float* rb3 = (const float*)d_in[14];
    float* outp = (float*)d_out;

    char* ws = (char*)d_ws;
    size_t off = 0;
    auto alloc = [&](size_t bytes) {
        char* p = ws + off;
        off += (bytes + 255) & ~(size_t)255;
        return p;
    };
    __hip_bfloat16* c1out = (__hip_bfloat16*)alloc(150994944UL);  // [128][48][48][256] bf16
    __hip_bfloat16* c2out = (__hip_bfloat16*)alloc(26214400UL);   // [128][20][20][256]
    __hip_bfloat16* c3out = (__hip_bfloat16*)alloc(2359296UL);    // [128][6][6][256]
    __hip_bfloat16* w2p   = (__hip_bfloat16*)alloc(10616832UL);
    __hip_bfloat16* w3p   = (__hip_bfloat16*)alloc(10616832UL);
    float* u     = (float*)alloc(4718592UL);    // [128][1152][8] f32
    __hip_bfloat16* uhat = (__hip_bfloat16*)alloc(47185920UL);  // [128][10][1152][16] bf16
    float* vws   = (float*)alloc(81920UL);      // [128][160]
    float* rec1  = (float*)alloc(262144UL);     // [128][512]
    float* rec2  = (float*)alloc(524288UL);     // [128][1024]

    prep_w_kernel<<<512, 256, 0, stream>>>(c2w, w2p);
    prep_w_kernel<<<512, 256, 0, stream>>>(pw, w3p);
    conv1_kernel<<<dim3(48, 128), 256, 0, stream>>>(x, c1w, c1b, c1out);
    conv_mfma_kernel<<<dim3(400, 2), 256, 0, stream>>>(c1out, w2p, c2b, c2out, 48, 48 * 48 * 256, 400, 20);
    conv_mfma_kernel<<<dim3(36, 2), 256, 0, stream>>>(c2out, w3p, pb, c3out, 20, 20 * 20 * 256, 36, 6);
    squash_caps_kernel<<<576, 256, 0, stream>>>(c3out, u);
    uhat_kernel<<<1152, 256, 0, stream>>>(u, Wd, uhat);
    routing_kernel<<<1280, 256, 0, stream>>>(uhat, bd, outp, vws);
    rec_gemm_kernel<<<dim3(8, 4), 256, 0, stream>>>(vws, rw1, rb1, rec1, 160, 512, 0);
    rec_gemm_kernel<<<dim3(16, 4), 256, 0, stream>>>(rec1, rw2, rb2, rec2, 512, 1024, 0);
    rec_gemm_kernel<<<dim3(49, 4), 256, 0, stream>>>(rec2, rw3, rb3, outp + 20480, 1024, 3136, 1);
}

// Round 2
// 1930.390 us; speedup vs baseline: 1.1882x; 1.1882x over previous
//
#include <hip/hip_runtime.h>
#include <hip/hip_bf16.h>

typedef float f32x4 __attribute__((ext_vector_type(4)));
typedef __bf16 bf16x8 __attribute__((ext_vector_type(8)));

#define AS1 __attribute__((address_space(1)))
#define AS3 __attribute__((address_space(3)))

__device__ __forceinline__ void gload16(const void* g, void* l) {
    __builtin_amdgcn_global_load_lds((AS1 unsigned int*)g, (AS3 unsigned int*)l, 16, 0, 0);
}

__device__ __forceinline__ float bfu(unsigned short u) {
    return __uint_as_float((unsigned)u << 16);
}

// ---------------- weight prep: OIHW f32 -> [kyx][icg][nblk][oc128][ic32] bf16 ----------------
__global__ __launch_bounds__(256) void prep_w_kernel(const float* __restrict__ w,
                                                     __hip_bfloat16* __restrict__ wp) {
    __shared__ float wl[4 * 32 * 81];  // [o][i][kyx]
    int bid = blockIdx.x;
    int icg = bid & 7;
    int oc4 = (bid >> 3) & 31;
    int nblk = bid >> 8;
    int t = threadIdx.x;
    int ocg0 = nblk * 128 + oc4 * 4;
    int ic0 = icg * 32;
    for (int f = t; f < 4 * 2592; f += 256) {
        int o = f / 2592;
        int rest = f - o * 2592;  // i*81 + kyx
        wl[f] = w[(ocg0 + o) * 20736 + ic0 * 81 + rest];
    }
    __syncthreads();
    for (int idx = t; idx < 81 * 128; idx += 256) {
        int kyx = idx >> 7;
        int o = (idx >> 5) & 3;
        int i = idx & 31;
        long dst = (long)(((kyx * 8 + icg) * 2 + nblk) * 128 + (oc4 * 4 + o)) * 32 + i;
        wp[dst] = __float2bfloat16(wl[o * 2592 + i * 81 + kyx]);
    }
}

// ---------------- conv1: 1->256ch 9x9 s1, f32 compute, NHWC bf16 out + relu ----------------
__global__ __launch_bounds__(256) void conv1_kernel(const float* __restrict__ x,
                                                    const float* __restrict__ w,
                                                    const float* __restrict__ bias,
                                                    __hip_bfloat16* __restrict__ out) {
    __shared__ float rowb[504];  // 9 rows x 56
    int oy = blockIdx.x;  // 0..47
    int b = blockIdx.y;   // 0..127
    int t = threadIdx.x;  // = oc
    const float* src = x + b * 3136 + oy * 56;
    for (int i = t; i < 504; i += 256) rowb[i] = src[i];
    __syncthreads();
    const float* wp = w + t * 81;
    float acc[48];
#pragma unroll
    for (int i = 0; i < 48; ++i) acc[i] = 0.f;
    for (int ky = 0; ky < 9; ++ky) {
        float r[56];
#pragma unroll
        for (int i = 0; i < 56; ++i) r[i] = rowb[ky * 56 + i];
#pragma unroll
        for (int kx = 0; kx < 9; ++kx) {
            float wv = wp[ky * 9 + kx];
#pragma unroll
            for (int ox = 0; ox < 48; ++ox) acc[ox] = fmaf(wv, r[ox + kx], acc[ox]);
        }
    }
    float bs = bias[t];
    __hip_bfloat16* op = out + ((b * 48 + oy) * 48) * 256 + t;
#pragma unroll
    for (int ox = 0; ox < 48; ++ox) {
        float v = acc[ox] + bs;
        v = v > 0.f ? v : 0.f;
        op[ox * 256] = __float2bfloat16(v);
    }
}

// ---------------- implicit-GEMM conv (bf16 MFMA), NHWC in/out ----------------
// Double-buffered BK=32, XOR-swizzled LDS (swizzle applied at global source + ds_read addr).
// mode 0: bias+relu+bf16 out. mode 1: f32 partial (split-K), no bias.
__global__ __launch_bounds__(256) void conv_mfma_kernel(const __hip_bfloat16* __restrict__ in,
                                                        const __hip_bfloat16* __restrict__ wp,
                                                        const float* __restrict__ bias,
                                                        __hip_bfloat16* __restrict__ out,
                                                        float* __restrict__ part,
                                                        int Win, int imgStride, int HWout, int Wout,
                                                        int nkyx, int Mtot, int mode) {
    __shared__ __hip_bfloat16 Ald[8192];  // 2 bufs x [row128][k32]
    __shared__ __hip_bfloat16 Bld[8192];  // 2 bufs x [oc128][k32]
    int mblk = blockIdx.x, nblk = blockIdx.y;
    int kyx0 = blockIdx.z * nkyx;
    int t = threadIdx.x;
    int lane = t & 63, wid = t >> 6;
    // swizzled source slot within the 32-ch k-group: slot' = slot ^ ((row>>1)&3)
    int swz = ((t & 3) ^ ((t >> 3) & 3)) * 8;
    int icsrc = swz;                       // A source elem offset within k-group
    long bsrc = (t >> 2) * 32 + swz;       // B source elem offset within tile

    long base0, base1;
    {
        int m = mblk * 128 + (t >> 2);
        int b = m / HWout; int rem = m - b * HWout;
        int oyy = rem / Wout; int oxx = rem - oyy * Wout;
        base0 = (long)b * imgStride + (long)(2 * oyy * Win + 2 * oxx) * 256;
        m += 64;
        b = m / HWout; rem = m - b * HWout;
        oyy = rem / Wout; oxx = rem - oyy * Wout;
        base1 = (long)b * imgStride + (long)(2 * oyy * Win + 2 * oxx) * 256;
    }

    f32x4 acc[4][4];
#pragma unroll
    for (int i = 0; i < 4; ++i)
#pragma unroll
        for (int j2 = 0; j2 < 4; ++j2) acc[i][j2] = (f32x4){0.f, 0.f, 0.f, 0.f};

    int wr = wid >> 1, wc = wid & 1;
    // reader swizzle: want slot (lane>>4); read slot (lane>>4) ^ ((row>>1)&3), row low bits = lane&15
    int slot8 = (((lane >> 4) ^ ((lane >> 1) & 3))) * 8;
    int a_off = ((wr * 64 + (lane & 15)) * 32 + slot8) * 2;  // bytes
    int b_off = ((wc * 64 + (lane & 15)) * 32 + slot8) * 2;

    auto stage = [&](int s, int buf) {
        int kyx = kyx0 + (s >> 3);
        int icg = s & 7;
        int ky = kyx / 9, kx = kyx - ky * 9;
        long offA = (long)(ky * Win + kx) * 256 + icg * 32 + icsrc;
        long btb = (long)((kyx * 8 + icg) * 2 + nblk) * 4096 + bsrc;
        char* a0 = (char*)Ald + buf * 8192 + wid * 1024;
        char* b0 = (char*)Bld + buf * 8192 + wid * 1024;
        gload16(in + base0 + offA, a0);
        gload16(in + base1 + offA, a0 + 4096);
        gload16(wp + btb, b0);
        gload16(wp + btb + 2048, b0 + 4096);
    };

    int nsteps = nkyx * 8;
    stage(0, 0);
    __syncthreads();
    for (int s = 0; s < nsteps; ++s) {
        int cur = s & 1;
        if (s + 1 < nsteps) stage(s + 1, cur ^ 1);
        const char* Ac = (const char*)Ald + cur * 8192;
        const char* Bc = (const char*)Bld + cur * 8192;
        bf16x8 af[4], bfr[4];
#pragma unroll
        for (int i = 0; i < 4; ++i) af[i] = *(const bf16x8*)(Ac + a_off + i * 1024);
#pragma unroll
        for (int i = 0; i < 4; ++i) bfr[i] = *(const bf16x8*)(Bc + b_off + i * 1024);
#pragma unroll
        for (int mi = 0; mi < 4; ++mi)
#pragma unroll
            for (int ni = 0; ni < 4; ++ni)
                acc[mi][ni] = __builtin_amdgcn_mfma_f32_16x16x32_bf16(af[mi], bfr[ni], acc[mi][ni], 0, 0, 0);
        __syncthreads();
    }

    int colbase = nblk * 128 + wc * 64 + (lane & 15);
    long mrowbase = (long)mblk * 128 + wr * 64 + (lane >> 4) * 4;
    if (mode == 0) {
#pragma unroll
        for (int mi = 0; mi < 4; ++mi) {
#pragma unroll
            for (int ni = 0; ni < 4; ++ni) {
                int col = colbase + ni * 16;
                float bs = bias[col];
#pragma unroll
                for (int r = 0; r < 4; ++r) {
                    long mrow = mrowbase + mi * 16 + r;
                    float v = acc[mi][ni][r] + bs;
                    v = v > 0.f ? v : 0.f;
                    out[mrow * 256 + col] = __float2bfloat16(v);
                }
            }
        }
    } else {
        float* pp = part + (long)blockIdx.z * Mtot * 256;
#pragma unroll
        for (int mi = 0; mi < 4; ++mi) {
#pragma unroll
            for (int ni = 0; ni < 4; ++ni) {
                int col = colbase + ni * 16;
#pragma unroll
                for (int r = 0; r < 4; ++r) {
                    long mrow = mrowbase + mi * 16 + r;
                    pp[mrow * 256 + col] = acc[mi][ni][r];
                }
            }
        }
    }
}

// ---------------- split-K reduce: sum 9 partials + bias + relu -> bf16 NHWC ----------------
__global__ __launch_bounds__(256) void reduce_parts_kernel(const float* __restrict__ part,
                                                           const float* __restrict__ bias,
                                                           __hip_bfloat16* __restrict__ out) {
    int idx = blockIdx.x * 256 + threadIdx.x;  // 4608*256
    float s = 0.f;
#pragma unroll
    for (int p = 0; p < 9; ++p) s += part[(long)p * 1179648 + idx];
    s += bias[idx & 255];
    s = s > 0.f ? s : 0.f;
    out[idx] = __float2bfloat16(s);
}

// ---------------- primary capsule squash: NHWC bf16 -> u f32 [B,1152,8] ----------------
__global__ __launch_bounds__(256) void squash_caps_kernel(const __hip_bfloat16* __restrict__ c3,
                                                          float* __restrict__ u) {
    int g = blockIdx.x * 256 + threadIdx.x;  // 147456 = 128*1152
    int b = g / 1152, i = g - b * 1152;
    float val[8];
    float sn = 0.f;
#pragma unroll
    for (int d = 0; d < 8; ++d) {
        int flat = i * 8 + d;
        int c = flat / 36; int rem = flat - c * 36;
        int y = rem / 6; int xx = rem - y * 6;
        float vv = __bfloat162float(c3[((b * 6 + y) * 6 + xx) * 256 + c]);
        val[d] = vv;
        sn += vv * vv;
    }
    float sc = (sn / (1.f + sn)) / sqrtf(sn + 1e-8f);
#pragma unroll
    for (int d = 0; d < 8; ++d) u[(long)g * 8 + d] = val[d] * sc;
}

// ---------------- u_hat[b,j,i,o] = sum_d u[b,i,d] * W[j,i,d,o]  (bf16 out, [b][j][i][o]) ----------------
__global__ __launch_bounds__(256) void uhat_kernel(const float* __restrict__ u,
                                                   const float* __restrict__ Wd,
                                                   __hip_bfloat16* __restrict__ uhat) {
    __shared__ float Wl[1280];  // [j][d][o]
    __shared__ float ul[1024];  // [b][d]
    int i = blockIdx.x, t = threadIdx.x;
    for (int idx = t; idx < 1280; idx += 256) {
        int j = idx >> 7, rest = idx & 127;
        Wl[idx] = Wd[((long)j * 1152 + i) * 128 + rest];
    }
    for (int idx = t; idx < 1024; idx += 256) {
        int b = idx >> 3, d = idx & 7;
        ul[idx] = u[((long)b * 1152 + i) * 8 + d];
    }
    __syncthreads();
    for (int rr = 0; rr < 80; ++rr) {
        int idx = rr * 256 + t;
        int b = idx / 160; int jo = idx - b * 160;
        int j = jo >> 4, o = jo & 15;
        float a = 0.f;
#pragma unroll
        for (int d = 0; d < 8; ++d) a += ul[b * 8 + d] * Wl[j * 128 + d * 16 + o];
        uhat[(((long)b * 10 + j) * 1152 + i) * 16 + o] = __float2bfloat16(a);
    }
}

// ---------------- fused dynamic routing per (b,j): 3 iterations in LDS ----------------
__global__ __launch_bounds__(256) void routing_kernel(const __hip_bfloat16* __restrict__ uhat,
                                                      const float* __restrict__ bdig,
                                                      float* __restrict__ vout,
                                                      float* __restrict__ vws) {
    __shared__ __hip_bfloat16 uh[1152 * 16];  // 36864B
    __shared__ float barr[1152];
    __shared__ float red[16];
    __shared__ float accb[16 * 256];          // 16KB
    __shared__ float svec[16];
    __shared__ float vsc[16];
    int bid = blockIdx.x;  // b*10 + j
    int j = bid % 10;
    int t = threadIdx.x;
    int wid = t >> 6;
    const uint4* srcp = (const uint4*)(uhat + (long)bid * 18432);
    uint4* dstp = (uint4*)uh;
    for (int idx = t; idx < 2304; idx += 256) dstp[idx] = srcp[idx];
    for (int idx = t; idx < 1152; idx += 256) barr[idx] = 0.f;
    __syncthreads();
    for (int it = 0; it < 3; ++it) {
        // ---- max over b ----
        float lm = -1e30f;
        for (int i = t; i < 1152; i += 256) lm = fmaxf(lm, barr[i]);
#pragma unroll
        for (int m2 = 32; m2; m2 >>= 1) lm = fmaxf(lm, __shfl_xor(lm, m2));
        if ((t & 63) == 0) red[wid] = lm;
        __syncthreads();
        float mx = fmaxf(fmaxf(red[0], red[1]), fmaxf(red[2], red[3]));
        // ---- e-weighted accumulate ----
        float le = 0.f;
        float a16[16];
#pragma unroll
        for (int o = 0; o < 16; ++o) a16[o] = 0.f;
        for (int i = t; i < 1152; i += 256) {
            float e = __expf(barr[i] - mx);
            le += e;
            const uint4* up = (const uint4*)(uh + i * 16);
            union { uint4 q; unsigned short s[8]; } U0, U1;
            U0.q = up[0]; U1.q = up[1];
#pragma unroll
            for (int o = 0; o < 8; ++o) a16[o] += e * bfu(U0.s[o]);
#pragma unroll
            for (int o = 0; o < 8; ++o) a16[8 + o] += e * bfu(U1.s[o]);
        }
#pragma unroll
        for (int m2 = 32; m2; m2 >>= 1) le += __shfl_xor(le, m2);
        if ((t & 63) == 0) red[4 + wid] = le;
#pragma unroll
        for (int o = 0; o < 16; ++o) accb[o * 256 + t] = a16[o];
        __syncthreads();
        float sume = red[4] + red[5] + red[6] + red[7];
        // ---- transpose reduce: group g (=o) of 16 threads ----
        int g = t >> 4, tin = t & 15;
        float s = 0.f;
#pragma unroll
        for (int k = 0; k < 16; ++k) s += accb[g * 256 + tin + 16 * k];
#pragma unroll
        for (int m2 = 8; m2; m2 >>= 1) s += __shfl_xor(s, m2);
        if (tin == 0) svec[g] = s / sume + bdig[j * 16 + g];
        __syncthreads();
        // ---- squash (16 lanes of wave 0) ----
        if (t < 16) {
            float sv = svec[t];
            float sn = sv * sv;
#pragma unroll
            for (int m2 = 8; m2; m2 >>= 1) sn += __shfl_xor(sn, m2);
            float sc = (sn / (1.f + sn)) / sqrtf(sn + 1e-8f);
            float v = sv * sc;
            vsc[t] = v;
            if (it == 2) { vout[bid * 16 + t] = v; vws[bid * 16 + t] = v; }
        }
        __syncthreads();
        if (it < 2) {
            for (int i = t; i < 1152; i += 256) {
                const uint4* up = (const uint4*)(uh + i * 16);
                union { uint4 q; unsigned short s[8]; } U0, U1;
                U0.q = up[0]; U1.q = up[1];
                float dot = 0.f;
#pragma unroll
                for (int o = 0; o < 8; ++o) dot += vsc[o] * bfu(U0.s[o]);
#pragma unroll
                for (int o = 0; o < 8; ++o) dot += vsc[8 + o] * bfu(U1.s[o]);
                barr[i] += dot;
            }
            __syncthreads();
        }
    }
}

// ---------------- reconstruction GEMM: out[128,N] = act(A[128,K] x W[K,N] + bias) ----------------
__global__ __launch_bounds__(256) void rec_gemm_kernel(const float* __restrict__ A,
                                                       const float* __restrict__ W,
                                                       const float* __restrict__ bias,
                                                       float* __restrict__ out,
                                                       int K, int N, int act) {
    __shared__ float As[32 * 64];
    int n0 = blockIdx.x * 64;
    int bch = blockIdx.y * 32;
    int t = threadIdx.x;
    int n_l = t & 63, bh = t >> 6;
    float acc[8];
#pragma unroll
    for (int i = 0; i < 8; ++i) acc[i] = 0.f;
    for (int k0 = 0; k0 < K; k0 += 64) {
        int kc = K - k0;
        if (kc > 64) kc = 64;
        __syncthreads();
        for (int idx = t; idx < 2048; idx += 256) {
            int bb = idx >> 6, kk = idx & 63;
            if (kk < kc) As[idx] = A[(long)(bch + bb) * K + k0 + kk];
        }
        __syncthreads();
        for (int kk = 0; kk < kc; ++kk) {
            float wv = W[(long)(k0 + kk) * N + n0 + n_l];
#pragma unroll
            for (int bb = 0; bb < 8; ++bb) acc[bb] += As[(bh * 8 + bb) * 64 + kk] * wv;
        }
    }
    float bs = bias[n0 + n_l];
    for (int bb = 0; bb < 8; ++bb) {
        float x = acc[bb] + bs;
        float r;
        if (act == 0) r = x > 0.f ? x : 0.f;
        else r = 1.f / (1.f + __expf(-x));
        out[(long)(bch + bh * 8 + bb) * N + n0 + n_l] = r;
    }
}

extern "C" void kernel_launch(void* const* d_in, const int* in_sizes, int n_in,
                              void* d_out, int out_size, void* d_ws, size_t ws_size,
                              hipStream_t stream) {
    const float* x   = (const float*)d_in[0];
    const float* c1w = (const float*)d_in[1];
    const float* c1b = (const float*)d_in[2];
    const float* c2w = (const float*)d_in[3];
    const float* c2b = (const float*)d_in[4];
    const float* pw  = (const float*)d_in[5];
    const float* pb  = (const float*)d_in[6];
    const float* Wd  = (const float*)d_in[7];
    const float* bd  = (const float*)d_in[8];
    const float* rw1 = (const float*)d_in[9];
    const float* rb1 = (const float*)d_in[10];
    const float* rw2 = (const float*)d_in[11];
    const float* rb2 = (const float*)d_in[12];
    const float* rw3 = (const float*)d_in[13];
    const float* rb3 = (const float*)d_in[14];
    float* outp = (float*)d_out;

    char* ws = (char*)d_ws;
    size_t off = 0;
    auto alloc = [&](size_t bytes) {
        char* p = ws + off;
        off += (bytes + 255) & ~(size_t)255;
        return p;
    };
    __hip_bfloat16* c1out = (__hip_bfloat16*)alloc(150994944UL);  // [128][48][48][256] bf16
    __hip_bfloat16* c2out = (__hip_bfloat16*)alloc(26214400UL);   // [128][20][20][256]
    __hip_bfloat16* c3out = (__hip_bfloat16*)alloc(2359296UL);    // [128][6][6][256]
    __hip_bfloat16* w2p   = (__hip_bfloat16*)alloc(10616832UL);
    __hip_bfloat16* w3p   = (__hip_bfloat16*)alloc(10616832UL);
    float* u     = (float*)alloc(4718592UL);    // [128][1152][8] f32
    __hip_bfloat16* uhat = (__hip_bfloat16*)alloc(47185920UL);  // [128][10][1152][16] bf16
    float* vws   = (float*)alloc(81920UL);      // [128][160]
    float* rec1  = (float*)alloc(262144UL);     // [128][512]
    float* rec2  = (float*)alloc(524288UL);     // [128][1024]

    // conv3 split-K partials [9][4608][256] f32 = 42.5MB alias the (later-written) uhat buffer
    float* c3part = (float*)uhat;

    prep_w_kernel<<<512, 256, 0, stream>>>(c2w, w2p);
    prep_w_kernel<<<512, 256, 0, stream>>>(pw, w3p);
    conv1_kernel<<<dim3(48, 128), 256, 0, stream>>>(x, c1w, c1b, c1out);
    conv_mfma_kernel<<<dim3(400, 2, 1), 256, 0, stream>>>(c1out, w2p, c2b, c2out, nullptr,
                                                          48, 48 * 48 * 256, 400, 20, 81, 51200, 0);
    conv_mfma_kernel<<<dim3(36, 2, 9), 256, 0, stream>>>(c2out, w3p, pb, c3out, c3part,
                                                         20, 20 * 20 * 256, 36, 6, 9, 4608, 1);
    reduce_parts_kernel<<<4608, 256, 0, stream>>>(c3part, pb, c3out);
    squash_caps_kernel<<<576, 256, 0, stream>>>(c3out, u);
    uhat_kernel<<<1152, 256, 0, stream>>>(u, Wd, uhat);
    routing_kernel<<<1280, 256, 0, stream>>>(uhat, bd, outp, vws);
    rec_gemm_kernel<<<dim3(8, 4), 256, 0, stream>>>(vws, rw1, rb1, rec1, 160, 512, 0);
    rec_gemm_kernel<<<dim3(16, 4), 256, 0, stream>>>(rec1, rw2, rb2, rec2, 512, 1024, 0);
    rec_gemm_kernel<<<dim3(49, 4), 256, 0, stream>>>(rec2, rw3, rb3, outp + 20480, 1024, 3136, 1);
}

// Round 3
// 1895.798 us; speedup vs baseline: 1.2099x; 1.0182x over previous
//
#include <hip/hip_runtime.h>
#include <hip/hip_bf16.h>

typedef float f32x4 __attribute__((ext_vector_type(4)));
typedef __bf16 bf16x8 __attribute__((ext_vector_type(8)));

#define AS1 __attribute__((address_space(1)))
#define AS3 __attribute__((address_space(3)))

__device__ __forceinline__ void gload16(const void* g, void* l) {
    __builtin_amdgcn_global_load_lds((AS1 unsigned int*)g, (AS3 unsigned int*)l, 16, 0, 0);
}

__device__ __forceinline__ float bfu(unsigned short u) {
    return __uint_as_float((unsigned)u << 16);
}

// ---------------- weight prep: OIHW f32 -> [kyx][icg][nblk][oc128][ic32] bf16 ----------------
__global__ __launch_bounds__(256) void prep_w_kernel(const float* __restrict__ w,
                                                     __hip_bfloat16* __restrict__ wp) {
    __shared__ float wl[4 * 32 * 81];  // [o][i][kyx]
    int bid = blockIdx.x;
    int icg = bid & 7;
    int oc4 = (bid >> 3) & 31;
    int nblk = bid >> 8;
    int t = threadIdx.x;
    int ocg0 = nblk * 128 + oc4 * 4;
    int ic0 = icg * 32;
    for (int f = t; f < 4 * 2592; f += 256) {
        int o = f / 2592;
        int rest = f - o * 2592;  // i*81 + kyx
        wl[f] = w[(ocg0 + o) * 20736 + ic0 * 81 + rest];
    }
    __syncthreads();
    for (int idx = t; idx < 81 * 128; idx += 256) {
        int kyx = idx >> 7;
        int o = (idx >> 5) & 3;
        int i = idx & 31;
        long dst = (long)(((kyx * 8 + icg) * 2 + nblk) * 128 + (oc4 * 4 + o)) * 32 + i;
        wp[dst] = __float2bfloat16(wl[o * 2592 + i * 81 + kyx]);
    }
}

// ---------------- conv1: 1->256ch 9x9 s1, f32 compute, NHWC bf16 out + relu ----------------
__global__ __launch_bounds__(256) void conv1_kernel(const float* __restrict__ x,
                                                    const float* __restrict__ w,
                                                    const float* __restrict__ bias,
                                                    __hip_bfloat16* __restrict__ out) {
    __shared__ float rowb[504];  // 9 rows x 56
    int oy = blockIdx.x;  // 0..47
    int b = blockIdx.y;   // 0..127
    int t = threadIdx.x;  // = oc
    const float* src = x + b * 3136 + oy * 56;
    for (int i = t; i < 504; i += 256) rowb[i] = src[i];
    __syncthreads();
    const float* wp = w + t * 81;
    float acc[48];
#pragma unroll
    for (int i = 0; i < 48; ++i) acc[i] = 0.f;
    for (int ky = 0; ky < 9; ++ky) {
        float r[56];
#pragma unroll
        for (int i = 0; i < 56; ++i) r[i] = rowb[ky * 56 + i];
#pragma unroll
        for (int kx = 0; kx < 9; ++kx) {
            float wv = wp[ky * 9 + kx];
#pragma unroll
            for (int ox = 0; ox < 48; ++ox) acc[ox] = fmaf(wv, r[ox + kx], acc[ox]);
        }
    }
    float bs = bias[t];
    __hip_bfloat16* op = out + ((b * 48 + oy) * 48) * 256 + t;
#pragma unroll
    for (int ox = 0; ox < 48; ++ox) {
        float v = acc[ox] + bs;
        v = v > 0.f ? v : 0.f;
        op[ox * 256] = __float2bfloat16(v);
    }
}

// ---------------- implicit-GEMM conv (bf16 MFMA), NHWC in/out ----------------
// Ring-3 LDS pipeline, counted vmcnt (never drain in main loop), XOR-swizzled LDS.
// mode 0: bias+relu+bf16 out. mode 1: f32 partial (split-K), no bias.
__global__ __launch_bounds__(256) void conv_mfma_kernel(const __hip_bfloat16* __restrict__ in,
                                                        const __hip_bfloat16* __restrict__ wp,
                                                        const float* __restrict__ bias,
                                                        __hip_bfloat16* __restrict__ out,
                                                        float* __restrict__ part,
                                                        int Win, int imgStride, int HWout, int Wout,
                                                        int nkyx, int Mtot, int mode) {
    __shared__ __hip_bfloat16 Ald[3 * 4096];  // 3 bufs x [row128][k32]
    __shared__ __hip_bfloat16 Bld[3 * 4096];  // 3 bufs x [oc128][k32]
    int mblk = blockIdx.x, nblk = blockIdx.y;
    int kyx0 = blockIdx.z * nkyx;
    int t = threadIdx.x;
    int lane = t & 63, wid = t >> 6;
    // swizzled source slot within the 32-ch k-group: slot' = slot ^ ((row>>1)&3)
    int swz = ((t & 3) ^ ((t >> 3) & 3)) * 8;
    int icsrc = swz;                       // A source elem offset within k-group
    long bsrc = (t >> 2) * 32 + swz;       // B source elem offset within tile

    long base0, base1;
    {
        int m = mblk * 128 + (t >> 2);
        int b = m / HWout; int rem = m - b * HWout;
        int oyy = rem / Wout; int oxx = rem - oyy * Wout;
        base0 = (long)b * imgStride + (long)(2 * oyy * Win + 2 * oxx) * 256;
        m += 64;
        b = m / HWout; rem = m - b * HWout;
        oyy = rem / Wout; oxx = rem - oyy * Wout;
        base1 = (long)b * imgStride + (long)(2 * oyy * Win + 2 * oxx) * 256;
    }

    f32x4 acc[4][4];
#pragma unroll
    for (int i = 0; i < 4; ++i)
#pragma unroll
        for (int j2 = 0; j2 < 4; ++j2) acc[i][j2] = (f32x4){0.f, 0.f, 0.f, 0.f};

    int wr = wid >> 1, wc = wid & 1;
    // reader swizzle: want slot (lane>>4); read slot (lane>>4) ^ ((row>>1)&3), row low bits = lane&15
    int slot8 = (((lane >> 4) ^ ((lane >> 1) & 3))) * 8;
    int a_off = ((wr * 64 + (lane & 15)) * 32 + slot8) * 2;  // bytes
    int b_off = ((wc * 64 + (lane & 15)) * 32 + slot8) * 2;

    auto stage = [&](int s, int buf) {
        int kyx = kyx0 + (s >> 3);
        int icg = s & 7;
        int ky = kyx / 9, kx = kyx - ky * 9;
        long offA = (long)(ky * Win + kx) * 256 + icg * 32 + icsrc;
        long btb = (long)((kyx * 8 + icg) * 2 + nblk) * 4096 + bsrc;
        char* a0 = (char*)Ald + buf * 8192 + wid * 1024;
        char* b0 = (char*)Bld + buf * 8192 + wid * 1024;
        gload16(in + base0 + offA, a0);
        gload16(in + base1 + offA, a0 + 4096);
        gload16(wp + btb, b0);
        gload16(wp + btb + 2048, b0 + 4096);
    };

    int nsteps = nkyx * 8;
    stage(0, 0);
    stage(1, 1);
    stage(2, 2);
    int cur = 0;
    for (int s = 0; s < nsteps; ++s) {
        int rem = nsteps - 1 - s;
        if (rem >= 2) {
            asm volatile("s_waitcnt vmcnt(8)" ::: "memory");
        } else if (rem == 1) {
            asm volatile("s_waitcnt vmcnt(4)" ::: "memory");
        } else {
            asm volatile("s_waitcnt vmcnt(0)" ::: "memory");
        }
        __builtin_amdgcn_s_barrier();
        __builtin_amdgcn_sched_barrier(0);
        const char* Ac = (const char*)Ald + cur * 8192;
        const char* Bc = (const char*)Bld + cur * 8192;
        bf16x8 af[4], bfr[4];
#pragma unroll
        for (int i = 0; i < 4; ++i) af[i] = *(const bf16x8*)(Ac + a_off + i * 1024);
#pragma unroll
        for (int i = 0; i < 4; ++i) bfr[i] = *(const bf16x8*)(Bc + b_off + i * 1024);
#pragma unroll
        for (int mi = 0; mi < 4; ++mi)
#pragma unroll
            for (int ni = 0; ni < 4; ++ni)
                acc[mi][ni] = __builtin_amdgcn_mfma_f32_16x16x32_bf16(af[mi], bfr[ni], acc[mi][ni], 0, 0, 0);
        if (s + 3 < nsteps) {
            asm volatile("s_waitcnt lgkmcnt(0)" ::: "memory");
            __builtin_amdgcn_s_barrier();
            stage(s + 3, cur);
        }
        cur = (cur == 2) ? 0 : cur + 1;
    }

    int colbase = nblk * 128 + wc * 64 + (lane & 15);
    long mrowbase = (long)mblk * 128 + wr * 64 + (lane >> 4) * 4;
    if (mode == 0) {
#pragma unroll
        for (int mi = 0; mi < 4; ++mi) {
#pragma unroll
            for (int ni = 0; ni < 4; ++ni) {
                int col = colbase + ni * 16;
                float bs = bias[col];
#pragma unroll
                for (int r = 0; r < 4; ++r) {
                    long mrow = mrowbase + mi * 16 + r;
                    float v = acc[mi][ni][r] + bs;
                    v = v > 0.f ? v : 0.f;
                    out[mrow * 256 + col] = __float2bfloat16(v);
                }
            }
        }
    } else {
        float* pp = part + (long)blockIdx.z * Mtot * 256;
#pragma unroll
        for (int mi = 0; mi < 4; ++mi) {
#pragma unroll
            for (int ni = 0; ni < 4; ++ni) {
                int col = colbase + ni * 16;
#pragma unroll
                for (int r = 0; r < 4; ++r) {
                    long mrow = mrowbase + mi * 16 + r;
                    pp[mrow * 256 + col] = acc[mi][ni][r];
                }
            }
        }
    }
}

// ---------------- split-K reduce: sum 9 partials + bias + relu -> bf16 NHWC ----------------
__global__ __launch_bounds__(256) void reduce_parts_kernel(const float* __restrict__ part,
                                                           const float* __restrict__ bias,
                                                           __hip_bfloat16* __restrict__ out) {
    int idx = blockIdx.x * 256 + threadIdx.x;  // 4608*256
    float s = 0.f;
#pragma unroll
    for (int p = 0; p < 9; ++p) s += part[(long)p * 1179648 + idx];
    s += bias[idx & 255];
    s = s > 0.f ? s : 0.f;
    out[idx] = __float2bfloat16(s);
}

// ---------------- primary capsule squash: NHWC bf16 -> u f32 [B,1152,8] ----------------
__global__ __launch_bounds__(256) void squash_caps_kernel(const __hip_bfloat16* __restrict__ c3,
                                                          float* __restrict__ u) {
    int g = blockIdx.x * 256 + threadIdx.x;  // 147456 = 128*1152
    int b = g / 1152, i = g - b * 1152;
    float val[8];
    float sn = 0.f;
#pragma unroll
    for (int d = 0; d < 8; ++d) {
        int flat = i * 8 + d;
        int c = flat / 36; int rem = flat - c * 36;
        int y = rem / 6; int xx = rem - y * 6;
        float vv = __bfloat162float(c3[((b * 6 + y) * 6 + xx) * 256 + c]);
        val[d] = vv;
        sn += vv * vv;
    }
    float sc = (sn / (1.f + sn)) / sqrtf(sn + 1e-8f);
#pragma unroll
    for (int d = 0; d < 8; ++d) u[(long)g * 8 + d] = val[d] * sc;
}

// ---------------- u_hat[b,j,i,o] = sum_d u[b,i,d] * W[j,i,d,o]  (bf16 out, [b][j][i][o]) ----------------
__global__ __launch_bounds__(256) void uhat_kernel(const float* __restrict__ u,
                                                   const float* __restrict__ Wd,
                                                   __hip_bfloat16* __restrict__ uhat) {
    __shared__ float Wl[1280];  // [j][d][o]
    __shared__ float ul[1024];  // [b][d]
    int i = blockIdx.x, t = threadIdx.x;
    for (int idx = t; idx < 1280; idx += 256) {
        int j = idx >> 7, rest = idx & 127;
        Wl[idx] = Wd[((long)j * 1152 + i) * 128 + rest];
    }
    for (int idx = t; idx < 1024; idx += 256) {
        int b = idx >> 3, d = idx & 7;
        ul[idx] = u[((long)b * 1152 + i) * 8 + d];
    }
    __syncthreads();
    for (int rr = 0; rr < 80; ++rr) {
        int idx = rr * 256 + t;
        int b = idx / 160; int jo = idx - b * 160;
        int j = jo >> 4, o = jo & 15;
        float a = 0.f;
#pragma unroll
        for (int d = 0; d < 8; ++d) a += ul[b * 8 + d] * Wl[j * 128 + d * 16 + o];
        uhat[(((long)b * 10 + j) * 1152 + i) * 16 + o] = __float2bfloat16(a);
    }
}

// ---------------- fused dynamic routing per (b,j): 3 iterations in LDS ----------------
__global__ __launch_bounds__(256) void routing_kernel(const __hip_bfloat16* __restrict__ uhat,
                                                      const float* __restrict__ bdig,
                                                      float* __restrict__ vout,
                                                      float* __restrict__ vws) {
    __shared__ __hip_bfloat16 uh[1152 * 16];  // 36864B
    __shared__ float barr[1152];
    __shared__ float red[16];
    __shared__ float accb[16 * 256];          // 16KB
    __shared__ float svec[16];
    __shared__ float vsc[16];
    int bid = blockIdx.x;  // b*10 + j
    int j = bid % 10;
    int t = threadIdx.x;
    int wid = t >> 6;
    const uint4* srcp = (const uint4*)(uhat + (long)bid * 18432);
    uint4* dstp = (uint4*)uh;
    for (int idx = t; idx < 2304; idx += 256) dstp[idx] = srcp[idx];
    for (int idx = t; idx < 1152; idx += 256) barr[idx] = 0.f;
    __syncthreads();
    for (int it = 0; it < 3; ++it) {
        // ---- max over b ----
        float lm = -1e30f;
        for (int i = t; i < 1152; i += 256) lm = fmaxf(lm, barr[i]);
#pragma unroll
        for (int m2 = 32; m2; m2 >>= 1) lm = fmaxf(lm, __shfl_xor(lm, m2));
        if ((t & 63) == 0) red[wid] = lm;
        __syncthreads();
        float mx = fmaxf(fmaxf(red[0], red[1]), fmaxf(red[2], red[3]));
        // ---- e-weighted accumulate ----
        float le = 0.f;
        float a16[16];
#pragma unroll
        for (int o = 0; o < 16; ++o) a16[o] = 0.f;
        for (int i = t; i < 1152; i += 256) {
            float e = __expf(barr[i] - mx);
            le += e;
            const uint4* up = (const uint4*)(uh + i * 16);
            union { uint4 q; unsigned short s[8]; } U0, U1;
            U0.q = up[0]; U1.q = up[1];
#pragma unroll
            for (int o = 0; o < 8; ++o) a16[o] += e * bfu(U0.s[o]);
#pragma unroll
            for (int o = 0; o < 8; ++o) a16[8 + o] += e * bfu(U1.s[o]);
        }
#pragma unroll
        for (int m2 = 32; m2; m2 >>= 1) le += __shfl_xor(le, m2);
        if ((t & 63) == 0) red[4 + wid] = le;
#pragma unroll
        for (int o = 0; o < 16; ++o) accb[o * 256 + t] = a16[o];
        __syncthreads();
        float sume = red[4] + red[5] + red[6] + red[7];
        // ---- transpose reduce: group g (=o) of 16 threads ----
        int g = t >> 4, tin = t & 15;
        float s = 0.f;
#pragma unroll
        for (int k = 0; k < 16; ++k) s += accb[g * 256 + tin + 16 * k];
#pragma unroll
        for (int m2 = 8; m2; m2 >>= 1) s += __shfl_xor(s, m2);
        if (tin == 0) svec[g] = s / sume + bdig[j * 16 + g];
        __syncthreads();
        // ---- squash (16 lanes of wave 0) ----
        if (t < 16) {
            float sv = svec[t];
            float sn = sv * sv;
#pragma unroll
            for (int m2 = 8; m2; m2 >>= 1) sn += __shfl_xor(sn, m2);
            float sc = (sn / (1.f + sn)) / sqrtf(sn + 1e-8f);
            float v = sv * sc;
            vsc[t] = v;
            if (it == 2) { vout[bid * 16 + t] = v; vws[bid * 16 + t] = v; }
        }
        __syncthreads();
        if (it < 2) {
            for (int i = t; i < 1152; i += 256) {
                const uint4* up = (const uint4*)(uh + i * 16);
                union { uint4 q; unsigned short s[8]; } U0, U1;
                U0.q = up[0]; U1.q = up[1];
                float dot = 0.f;
#pragma unroll
                for (int o = 0; o < 8; ++o) dot += vsc[o] * bfu(U0.s[o]);
#pragma unroll
                for (int o = 0; o < 8; ++o) dot += vsc[8 + o] * bfu(U1.s[o]);
                barr[i] += dot;
            }
            __syncthreads();
        }
    }
}

// ---------------- reconstruction GEMM: out[128,N] = act(A[128,K] x W[K,N] + bias) ----------------
__global__ __launch_bounds__(256) void rec_gemm_kernel(const float* __restrict__ A,
                                                       const float* __restrict__ W,
                                                       const float* __restrict__ bias,
                                                       float* __restrict__ out,
                                                       int K, int N, int act) {
    __shared__ float As[32 * 64];
    int n0 = blockIdx.x * 64;
    int bch = blockIdx.y * 32;
    int t = threadIdx.x;
    int n_l = t & 63, bh = t >> 6;
    float acc[8];
#pragma unroll
    for (int i = 0; i < 8; ++i) acc[i] = 0.f;
    for (int k0 = 0; k0 < K; k0 += 64) {
        int kc = K - k0;
        if (kc > 64) kc = 64;
        __syncthreads();
        for (int idx = t; idx < 2048; idx += 256) {
            int bb = idx >> 6, kk = idx & 63;
            if (kk < kc) As[idx] = A[(long)(bch + bb) * K + k0 + kk];
        }
        __syncthreads();
        for (int kk = 0; kk < kc; ++kk) {
            float wv = W[(long)(k0 + kk) * N + n0 + n_l];
#pragma unroll
            for (int bb = 0; bb < 8; ++bb) acc[bb] += As[(bh * 8 + bb) * 64 + kk] * wv;
        }
    }
    float bs = bias[n0 + n_l];
    for (int bb = 0; bb < 8; ++bb) {
        float x = acc[bb] + bs;
        float r;
        if (act == 0) r = x > 0.f ? x : 0.f;
        else r = 1.f / (1.f + __expf(-x));
        out[(long)(bch + bh * 8 + bb) * N + n0 + n_l] = r;
    }
}

extern "C" void kernel_launch(void* const* d_in, const int* in_sizes, int n_in,
                              void* d_out, int out_size, void* d_ws, size_t ws_size,
                              hipStream_t stream) {
    const float* x   = (const float*)d_in[0];
    const float* c1w = (const float*)d_in[1];
    const float* c1b = (const float*)d_in[2];
    const float* c2w = (const float*)d_in[3];
    const float* c2b = (const float*)d_in[4];
    const float* pw  = (const float*)d_in[5];
    const float* pb  = (const float*)d_in[6];
    const float* Wd  = (const float*)d_in[7];
    const float* bd  = (const float*)d_in[8];
    const float* rw1 = (const float*)d_in[9];
    const float* rb1 = (const float*)d_in[10];
    const float* rw2 = (const float*)d_in[11];
    const float* rb2 = (const float*)d_in[12];
    const float* rw3 = (const float*)d_in[13];
    const float* rb3 = (const float*)d_in[14];
    float* outp = (float*)d_out;

    char* ws = (char*)d_ws;
    size_t off = 0;
    auto alloc = [&](size_t bytes) {
        char* p = ws + off;
        off += (bytes + 255) & ~(size_t)255;
        return p;
    };
    __hip_bfloat16* c1out = (__hip_bfloat16*)alloc(150994944UL);  // [128][48][48][256] bf16
    __hip_bfloat16* c2out = (__hip_bfloat16*)alloc(26214400UL);   // [128][20][20][256]
    __hip_bfloat16* c3out = (__hip_bfloat16*)alloc(2359296UL);    // [128][6][6][256]
    __hip_bfloat16* w2p   = (__hip_bfloat16*)alloc(10616832UL);
    __hip_bfloat16* w3p   = (__hip_bfloat16*)alloc(10616832UL);
    float* u     = (float*)alloc(4718592UL);    // [128][1152][8] f32
    __hip_bfloat16* uhat = (__hip_bfloat16*)alloc(47185920UL);  // [128][10][1152][16] bf16
    float* vws   = (float*)alloc(81920UL);      // [128][160]
    float* rec1  = (float*)alloc(262144UL);     // [128][512]
    float* rec2  = (float*)alloc(524288UL);     // [128][1024]

    // conv3 split-K partials [9][4608][256] f32 = 42.5MB alias the (later-written) uhat buffer
    float* c3part = (float*)uhat;

    prep_w_kernel<<<512, 256, 0, stream>>>(c2w, w2p);
    prep_w_kernel<<<512, 256, 0, stream>>>(pw, w3p);
    conv1_kernel<<<dim3(48, 128), 256, 0, stream>>>(x, c1w, c1b, c1out);
    conv_mfma_kernel<<<dim3(400, 2, 1), 256, 0, stream>>>(c1out, w2p, c2b, c2out, nullptr,
                                                          48, 48 * 48 * 256, 400, 20, 81, 51200, 0);
    conv_mfma_kernel<<<dim3(36, 2, 9), 256, 0, stream>>>(c2out, w3p, pb, c3out, c3part,
                                                         20, 20 * 20 * 256, 36, 6, 9, 4608, 1);
    reduce_parts_kernel<<<4608, 256, 0, stream>>>(c3part, pb, c3out);
    squash_caps_kernel<<<576, 256, 0, stream>>>(c3out, u);
    uhat_kernel<<<1152, 256, 0, stream>>>(u, Wd, uhat);
    routing_kernel<<<1280, 256, 0, stream>>>(uhat, bd, outp, vws);
    rec_gemm_kernel<<<dim3(8, 4), 256, 0, stream>>>(vws, rw1, rb1, rec1, 160, 512, 0);
    rec_gemm_kernel<<<dim3(16, 4), 256, 0, stream>>>(rec1, rw2, rb2, rec2, 512, 1024, 0);
    rec_gemm_kernel<<<dim3(49, 4), 256, 0, stream>>>(rec2, rw3, rb3, outp + 20480, 1024, 3136, 1);
}

// Round 4
// 1834.742 us; speedup vs baseline: 1.2501x; 1.0333x over previous
//
#include <hip/hip_runtime.h>
#include <hip/hip_bf16.h>

typedef float f32x4 __attribute__((ext_vector_type(4)));
typedef __bf16 bf16x8 __attribute__((ext_vector_type(8)));

#define AS1 __attribute__((address_space(1)))
#define AS3 __attribute__((address_space(3)))

__device__ __forceinline__ void gload16(const void* g, void* l) {
    __builtin_amdgcn_global_load_lds((AS1 unsigned int*)g, (AS3 unsigned int*)l, 16, 0, 0);
}

__device__ __forceinline__ float bfu(unsigned short u) {
    return __uint_as_float((unsigned)u << 16);
}

// ---------------- weight prep: OIHW f32 -> [kyx][icg][nblk][oc128][ic32] bf16 ----------------
__global__ __launch_bounds__(256) void prep_w_kernel(const float* __restrict__ w,
                                                     __hip_bfloat16* __restrict__ wp) {
    __shared__ float wl[4 * 32 * 81];  // [o][i][kyx]
    int bid = blockIdx.x;
    int icg = bid & 7;
    int oc4 = (bid >> 3) & 31;
    int nblk = bid >> 8;
    int t = threadIdx.x;
    int ocg0 = nblk * 128 + oc4 * 4;
    int ic0 = icg * 32;
    for (int f = t; f < 4 * 2592; f += 256) {
        int o = f / 2592;
        int rest = f - o * 2592;  // i*81 + kyx
        wl[f] = w[(ocg0 + o) * 20736 + ic0 * 81 + rest];
    }
    __syncthreads();
    for (int idx = t; idx < 81 * 128; idx += 256) {
        int kyx = idx >> 7;
        int o = (idx >> 5) & 3;
        int i = idx & 31;
        long dst = (long)(((kyx * 8 + icg) * 2 + nblk) * 128 + (oc4 * 4 + o)) * 32 + i;
        wp[dst] = __float2bfloat16(wl[o * 2592 + i * 81 + kyx]);
    }
}

// ---------------- conv1: 1->256ch 9x9 s1, f32 compute, NHWC bf16 out + relu ----------------
__global__ __launch_bounds__(256) void conv1_kernel(const float* __restrict__ x,
                                                    const float* __restrict__ w,
                                                    const float* __restrict__ bias,
                                                    __hip_bfloat16* __restrict__ out) {
    __shared__ float rowb[504];  // 9 rows x 56
    int oy = blockIdx.x;  // 0..47
    int b = blockIdx.y;   // 0..127
    int t = threadIdx.x;  // = oc
    const float* src = x + b * 3136 + oy * 56;
    for (int i = t; i < 504; i += 256) rowb[i] = src[i];
    __syncthreads();
    const float* wp = w + t * 81;
    float acc[48];
#pragma unroll
    for (int i = 0; i < 48; ++i) acc[i] = 0.f;
    for (int ky = 0; ky < 9; ++ky) {
        float r[56];
#pragma unroll
        for (int i = 0; i < 56; ++i) r[i] = rowb[ky * 56 + i];
#pragma unroll
        for (int kx = 0; kx < 9; ++kx) {
            float wv = wp[ky * 9 + kx];
#pragma unroll
            for (int ox = 0; ox < 48; ++ox) acc[ox] = fmaf(wv, r[ox + kx], acc[ox]);
        }
    }
    float bs = bias[t];
    __hip_bfloat16* op = out + ((b * 48 + oy) * 48) * 256 + t;
#pragma unroll
    for (int ox = 0; ox < 48; ++ox) {
        float v = acc[ox] + bs;
        v = v > 0.f ? v : 0.f;
        op[ox * 256] = __float2bfloat16(v);
    }
}

// ---------------- conv2: implicit-GEMM, 256x256 tile, 512 thr / 8 waves ----------------
// Ring-3 LDS pipeline, counted vmcnt, XOR-swizzled LDS, XCD-chunked block swizzle.
__global__ __launch_bounds__(512, 2) void conv_mfma256_kernel(const __hip_bfloat16* __restrict__ in,
                                                              const __hip_bfloat16* __restrict__ wp,
                                                              const float* __restrict__ bias,
                                                              __hip_bfloat16* __restrict__ out,
                                                              int Win, int imgStride, int HWout, int Wout,
                                                              int nMblk) {
    __shared__ __hip_bfloat16 Ald[3 * 8192];  // 3 bufs x [row256][k32] = 48KB
    __shared__ __hip_bfloat16 Bld[3 * 8192];  // 3 bufs x [oc256][k32]  = 48KB
    // bijective XCD-chunked swizzle (nMblk % 8 == 0)
    int bid = blockIdx.x;
    int cpx = nMblk >> 3;
    int mblk = (bid & 7) * cpx + (bid >> 3);
    int t = threadIdx.x;
    int lane = t & 63, wid = t >> 6;
    // staging swizzle: chunk' = (t&3) ^ ((row>>1)&3), row = t>>2 (mod 128 per pass)
    int swz = ((t & 3) ^ ((t >> 3) & 3)) * 8;  // elems
    int icsrc = swz;
    long bsrc = (t >> 2) * 32 + swz;

    long base0, base1;
    {
        int m = mblk * 256 + (t >> 2);
        int b = m / HWout; int rem = m - b * HWout;
        int oyy = rem / Wout; int oxx = rem - oyy * Wout;
        base0 = (long)b * imgStride + (long)(2 * oyy * Win + 2 * oxx) * 256;
        m += 128;
        b = m / HWout; rem = m - b * HWout;
        oyy = rem / Wout; oxx = rem - oyy * Wout;
        base1 = (long)b * imgStride + (long)(2 * oyy * Win + 2 * oxx) * 256;
    }

    f32x4 acc[8][4];
#pragma unroll
    for (int i = 0; i < 8; ++i)
#pragma unroll
        for (int j2 = 0; j2 < 4; ++j2) acc[i][j2] = (f32x4){0.f, 0.f, 0.f, 0.f};

    int wr = wid >> 2, wc = wid & 3;  // 2 x 4 wave grid; per-wave tile 128 x 64
    int slotB = (((lane >> 4) ^ ((lane >> 1) & 3))) * 16;  // bytes
    int a_off = (wr * 128 + (lane & 15)) * 64 + slotB;     // bytes
    int b_off = (wc * 64 + (lane & 15)) * 64 + slotB;

    auto stage = [&](int s, int buf) {
        int kyx = s >> 3;
        int icg = s & 7;
        int ky = kyx / 9, kx = kyx - ky * 9;
        long offA = (long)(ky * Win + kx) * 256 + icg * 32 + icsrc;
        long btb0 = (long)((kyx * 8 + icg) * 2 + 0) * 4096 + bsrc;
        long btb1 = (long)((kyx * 8 + icg) * 2 + 1) * 4096 + bsrc;
        char* a0 = (char*)Ald + buf * 16384 + wid * 1024;
        char* b0 = (char*)Bld + buf * 16384 + wid * 1024;
        gload16(in + base0 + offA, a0);          // A rows   0..127
        gload16(in + base1 + offA, a0 + 8192);   // A rows 128..255
        gload16(wp + btb0, b0);                  // B oc   0..127
        gload16(wp + btb1, b0 + 8192);           // B oc 128..255
    };

    const int nsteps = 648;
    stage(0, 0);
    stage(1, 1);
    stage(2, 2);
    int cur = 0;
    for (int s = 0; s < nsteps; ++s) {
        int rem = nsteps - 1 - s;
        if (rem >= 2) {
            asm volatile("s_waitcnt vmcnt(8)" ::: "memory");
        } else if (rem == 1) {
            asm volatile("s_waitcnt vmcnt(4)" ::: "memory");
        } else {
            asm volatile("s_waitcnt vmcnt(0)" ::: "memory");
        }
        __builtin_amdgcn_s_barrier();
        __builtin_amdgcn_sched_barrier(0);
        const char* Ac = (const char*)Ald + cur * 16384;
        const char* Bc = (const char*)Bld + cur * 16384;
        bf16x8 af[8], bfr[4];
#pragma unroll
        for (int i = 0; i < 8; ++i) af[i] = *(const bf16x8*)(Ac + a_off + i * 1024);
#pragma unroll
        for (int i = 0; i < 4; ++i) bfr[i] = *(const bf16x8*)(Bc + b_off + i * 1024);
#pragma unroll
        for (int mi = 0; mi < 8; ++mi)
#pragma unroll
            for (int ni = 0; ni < 4; ++ni)
                acc[mi][ni] = __builtin_amdgcn_mfma_f32_16x16x32_bf16(af[mi], bfr[ni], acc[mi][ni], 0, 0, 0);
        if (s + 3 < nsteps) {
            asm volatile("s_waitcnt lgkmcnt(0)" ::: "memory");
            __builtin_amdgcn_s_barrier();
            stage(s + 3, cur);
        }
        cur = (cur == 2) ? 0 : cur + 1;
    }

    int colbase = wc * 64 + (lane & 15);
    long mrowbase = (long)mblk * 256 + wr * 128 + (lane >> 4) * 4;
#pragma unroll
    for (int mi = 0; mi < 8; ++mi) {
#pragma unroll
        for (int ni = 0; ni < 4; ++ni) {
            int col = colbase + ni * 16;
            float bs = bias[col];
#pragma unroll
            for (int r = 0; r < 4; ++r) {
                long mrow = mrowbase + mi * 16 + r;
                float v = acc[mi][ni][r] + bs;
                v = v > 0.f ? v : 0.f;
                out[mrow * 256 + col] = __float2bfloat16(v);
            }
        }
    }
}

// ---------------- conv3: implicit-GEMM 128x128 (split-K), ring-3, counted vmcnt ----------------
__global__ __launch_bounds__(256) void conv_mfma_kernel(const __hip_bfloat16* __restrict__ in,
                                                        const __hip_bfloat16* __restrict__ wp,
                                                        const float* __restrict__ bias,
                                                        __hip_bfloat16* __restrict__ out,
                                                        float* __restrict__ part,
                                                        int Win, int imgStride, int HWout, int Wout,
                                                        int nkyx, int Mtot, int mode) {
    __shared__ __hip_bfloat16 Ald[3 * 4096];
    __shared__ __hip_bfloat16 Bld[3 * 4096];
    int mblk = blockIdx.x, nblk = blockIdx.y;
    int kyx0 = blockIdx.z * nkyx;
    int t = threadIdx.x;
    int lane = t & 63, wid = t >> 6;
    int swz = ((t & 3) ^ ((t >> 3) & 3)) * 8;
    int icsrc = swz;
    long bsrc = (t >> 2) * 32 + swz;

    long base0, base1;
    {
        int m = mblk * 128 + (t >> 2);
        int b = m / HWout; int rem = m - b * HWout;
        int oyy = rem / Wout; int oxx = rem - oyy * Wout;
        base0 = (long)b * imgStride + (long)(2 * oyy * Win + 2 * oxx) * 256;
        m += 64;
        b = m / HWout; rem = m - b * HWout;
        oyy = rem / Wout; oxx = rem - oyy * Wout;
        base1 = (long)b * imgStride + (long)(2 * oyy * Win + 2 * oxx) * 256;
    }

    f32x4 acc[4][4];
#pragma unroll
    for (int i = 0; i < 4; ++i)
#pragma unroll
        for (int j2 = 0; j2 < 4; ++j2) acc[i][j2] = (f32x4){0.f, 0.f, 0.f, 0.f};

    int wr = wid >> 1, wc = wid & 1;
    int slot8 = (((lane >> 4) ^ ((lane >> 1) & 3))) * 8;
    int a_off = ((wr * 64 + (lane & 15)) * 32 + slot8) * 2;
    int b_off = ((wc * 64 + (lane & 15)) * 32 + slot8) * 2;

    auto stage = [&](int s, int buf) {
        int kyx = kyx0 + (s >> 3);
        int icg = s & 7;
        int ky = kyx / 9, kx = kyx - ky * 9;
        long offA = (long)(ky * Win + kx) * 256 + icg * 32 + icsrc;
        long btb = (long)((kyx * 8 + icg) * 2 + nblk) * 4096 + bsrc;
        char* a0 = (char*)Ald + buf * 8192 + wid * 1024;
        char* b0 = (char*)Bld + buf * 8192 + wid * 1024;
        gload16(in + base0 + offA, a0);
        gload16(in + base1 + offA, a0 + 4096);
        gload16(wp + btb, b0);
        gload16(wp + btb + 2048, b0 + 4096);
    };

    int nsteps = nkyx * 8;
    stage(0, 0);
    stage(1, 1);
    stage(2, 2);
    int cur = 0;
    for (int s = 0; s < nsteps; ++s) {
        int rem = nsteps - 1 - s;
        if (rem >= 2) {
            asm volatile("s_waitcnt vmcnt(8)" ::: "memory");
        } else if (rem == 1) {
            asm volatile("s_waitcnt vmcnt(4)" ::: "memory");
        } else {
            asm volatile("s_waitcnt vmcnt(0)" ::: "memory");
        }
        __builtin_amdgcn_s_barrier();
        __builtin_amdgcn_sched_barrier(0);
        const char* Ac = (const char*)Ald + cur * 8192;
        const char* Bc = (const char*)Bld + cur * 8192;
        bf16x8 af[4], bfr[4];
#pragma unroll
        for (int i = 0; i < 4; ++i) af[i] = *(const bf16x8*)(Ac + a_off + i * 1024);
#pragma unroll
        for (int i = 0; i < 4; ++i) bfr[i] = *(const bf16x8*)(Bc + b_off + i * 1024);
#pragma unroll
        for (int mi = 0; mi < 4; ++mi)
#pragma unroll
            for (int ni = 0; ni < 4; ++ni)
                acc[mi][ni] = __builtin_amdgcn_mfma_f32_16x16x32_bf16(af[mi], bfr[ni], acc[mi][ni], 0, 0, 0);
        if (s + 3 < nsteps) {
            asm volatile("s_waitcnt lgkmcnt(0)" ::: "memory");
            __builtin_amdgcn_s_barrier();
            stage(s + 3, cur);
        }
        cur = (cur == 2) ? 0 : cur + 1;
    }

    int colbase = nblk * 128 + wc * 64 + (lane & 15);
    long mrowbase = (long)mblk * 128 + wr * 64 + (lane >> 4) * 4;
    if (mode == 0) {
#pragma unroll
        for (int mi = 0; mi < 4; ++mi) {
#pragma unroll
            for (int ni = 0; ni < 4; ++ni) {
                int col = colbase + ni * 16;
                float bs = bias[col];
#pragma unroll
                for (int r = 0; r < 4; ++r) {
                    long mrow = mrowbase + mi * 16 + r;
                    float v = acc[mi][ni][r] + bs;
                    v = v > 0.f ? v : 0.f;
                    out[mrow * 256 + col] = __float2bfloat16(v);
                }
            }
        }
    } else {
        float* pp = part + (long)blockIdx.z * Mtot * 256;
#pragma unroll
        for (int mi = 0; mi < 4; ++mi) {
#pragma unroll
            for (int ni = 0; ni < 4; ++ni) {
                int col = colbase + ni * 16;
#pragma unroll
                for (int r = 0; r < 4; ++r) {
                    long mrow = mrowbase + mi * 16 + r;
                    pp[mrow * 256 + col] = acc[mi][ni][r];
                }
            }
        }
    }
}

// ---------------- split-K reduce: sum 9 partials + bias + relu -> bf16 NHWC ----------------
__global__ __launch_bounds__(256) void reduce_parts_kernel(const float* __restrict__ part,
                                                           const float* __restrict__ bias,
                                                           __hip_bfloat16* __restrict__ out) {
    int idx = blockIdx.x * 256 + threadIdx.x;  // 4608*256
    float s = 0.f;
#pragma unroll
    for (int p = 0; p < 9; ++p) s += part[(long)p * 1179648 + idx];
    s += bias[idx & 255];
    s = s > 0.f ? s : 0.f;
    out[idx] = __float2bfloat16(s);
}

// ---------------- primary capsule squash: NHWC bf16 -> u f32 [B,1152,8] ----------------
__global__ __launch_bounds__(256) void squash_caps_kernel(const __hip_bfloat16* __restrict__ c3,
                                                          float* __restrict__ u) {
    int g = blockIdx.x * 256 + threadIdx.x;  // 147456 = 128*1152
    int b = g / 1152, i = g - b * 1152;
    float val[8];
    float sn = 0.f;
#pragma unroll
    for (int d = 0; d < 8; ++d) {
        int flat = i * 8 + d;
        int c = flat / 36; int rem = flat - c * 36;
        int y = rem / 6; int xx = rem - y * 6;
        float vv = __bfloat162float(c3[((b * 6 + y) * 6 + xx) * 256 + c]);
        val[d] = vv;
        sn += vv * vv;
    }
    float sc = (sn / (1.f + sn)) / sqrtf(sn + 1e-8f);
#pragma unroll
    for (int d = 0; d < 8; ++d) u[(long)g * 8 + d] = val[d] * sc;
}

// ---------------- u_hat[b,j,i,o] = sum_d u[b,i,d] * W[j,i,d,o]  (bf16 out, [b][j][i][o]) ----------------
__global__ __launch_bounds__(256) void uhat_kernel(const float* __restrict__ u,
                                                   const float* __restrict__ Wd,
                                                   __hip_bfloat16* __restrict__ uhat) {
    __shared__ float Wl[1280];  // [j][d][o]
    __shared__ float ul[1024];  // [b][d]
    int i = blockIdx.x, t = threadIdx.x;
    for (int idx = t; idx < 1280; idx += 256) {
        int j = idx >> 7, rest = idx & 127;
        Wl[idx] = Wd[((long)j * 1152 + i) * 128 + rest];
    }
    for (int idx = t; idx < 1024; idx += 256) {
        int b = idx >> 3, d = idx & 7;
        ul[idx] = u[((long)b * 1152 + i) * 8 + d];
    }
    __syncthreads();
    for (int rr = 0; rr < 80; ++rr) {
        int idx = rr * 256 + t;
        int b = idx / 160; int jo = idx - b * 160;
        int j = jo >> 4, o = jo & 15;
        float a = 0.f;
#pragma unroll
        for (int d = 0; d < 8; ++d) a += ul[b * 8 + d] * Wl[j * 128 + d * 16 + o];
        uhat[(((long)b * 10 + j) * 1152 + i) * 16 + o] = __float2bfloat16(a);
    }
}

// ---------------- fused dynamic routing per (b,j): 3 iterations in LDS ----------------
__global__ __launch_bounds__(256) void routing_kernel(const __hip_bfloat16* __restrict__ uhat,
                                                      const float* __restrict__ bdig,
                                                      float* __restrict__ vout,
                                                      float* __restrict__ vws) {
    __shared__ __hip_bfloat16 uh[1152 * 16];  // 36864B
    __shared__ float barr[1152];
    __shared__ float red[16];
    __shared__ float accb[16 * 256];          // 16KB
    __shared__ float svec[16];
    __shared__ float vsc[16];
    int bid = blockIdx.x;  // b*10 + j
    int j = bid % 10;
    int t = threadIdx.x;
    int wid = t >> 6;
    const uint4* srcp = (const uint4*)(uhat + (long)bid * 18432);
    uint4* dstp = (uint4*)uh;
    for (int idx = t; idx < 2304; idx += 256) dstp[idx] = srcp[idx];
    for (int idx = t; idx < 1152; idx += 256) barr[idx] = 0.f;
    __syncthreads();
    for (int it = 0; it < 3; ++it) {
        float lm = -1e30f;
        for (int i = t; i < 1152; i += 256) lm = fmaxf(lm, barr[i]);
#pragma unroll
        for (int m2 = 32; m2; m2 >>= 1) lm = fmaxf(lm, __shfl_xor(lm, m2));
        if ((t & 63) == 0) red[wid] = lm;
        __syncthreads();
        float mx = fmaxf(fmaxf(red[0], red[1]), fmaxf(red[2], red[3]));
        float le = 0.f;
        float a16[16];
#pragma unroll
        for (int o = 0; o < 16; ++o) a16[o] = 0.f;
        for (int i = t; i < 1152; i += 256) {
            float e = __expf(barr[i] - mx);
            le += e;
            const uint4* up = (const uint4*)(uh + i * 16);
            union { uint4 q; unsigned short s[8]; } U0, U1;
            U0.q = up[0]; U1.q = up[1];
#pragma unroll
            for (int o = 0; o < 8; ++o) a16[o] += e * bfu(U0.s[o]);
#pragma unroll
            for (int o = 0; o < 8; ++o) a16[8 + o] += e * bfu(U1.s[o]);
        }
#pragma unroll
        for (int m2 = 32; m2; m2 >>= 1) le += __shfl_xor(le, m2);
        if ((t & 63) == 0) red[4 + wid] = le;
#pragma unroll
        for (int o = 0; o < 16; ++o) accb[o * 256 + t] = a16[o];
        __syncthreads();
        float sume = red[4] + red[5] + red[6] + red[7];
        int g = t >> 4, tin = t & 15;
        float s = 0.f;
#pragma unroll
        for (int k = 0; k < 16; ++k) s += accb[g * 256 + tin + 16 * k];
#pragma unroll
        for (int m2 = 8; m2; m2 >>= 1) s += __shfl_xor(s, m2);
        if (tin == 0) svec[g] = s / sume + bdig[j * 16 + g];
        __syncthreads();
        if (t < 16) {
            float sv = svec[t];
            float sn = sv * sv;
#pragma unroll
            for (int m2 = 8; m2; m2 >>= 1) sn += __shfl_xor(sn, m2);
            float sc = (sn / (1.f + sn)) / sqrtf(sn + 1e-8f);
            float v = sv * sc;
            vsc[t] = v;
            if (it == 2) { vout[bid * 16 + t] = v; vws[bid * 16 + t] = v; }
        }
        __syncthreads();
        if (it < 2) {
            for (int i = t; i < 1152; i += 256) {
                const uint4* up = (const uint4*)(uh + i * 16);
                union { uint4 q; unsigned short s[8]; } U0, U1;
                U0.q = up[0]; U1.q = up[1];
                float dot = 0.f;
#pragma unroll
                for (int o = 0; o < 8; ++o) dot += vsc[o] * bfu(U0.s[o]);
#pragma unroll
                for (int o = 0; o < 8; ++o) dot += vsc[8 + o] * bfu(U1.s[o]);
                barr[i] += dot;
            }
            __syncthreads();
        }
    }
}

// ---------------- reconstruction GEMM: out[128,N] = act(A[128,K] x W[K,N] + bias) ----------------
__global__ __launch_bounds__(256) void rec_gemm_kernel(const float* __restrict__ A,
                                                       const float* __restrict__ W,
                                                       const float* __restrict__ bias,
                                                       float* __restrict__ out,
                                                       int K, int N, int act) {
    __shared__ float As[32 * 64];
    int n0 = blockIdx.x * 64;
    int bch = blockIdx.y * 32;
    int t = threadIdx.x;
    int n_l = t & 63, bh = t >> 6;
    float acc[8];
#pragma unroll
    for (int i = 0; i < 8; ++i) acc[i] = 0.f;
    for (int k0 = 0; k0 < K; k0 += 64) {
        int kc = K - k0;
        if (kc > 64) kc = 64;
        __syncthreads();
        for (int idx = t; idx < 2048; idx += 256) {
            int bb = idx >> 6, kk = idx & 63;
            if (kk < kc) As[idx] = A[(long)(bch + bb) * K + k0 + kk];
        }
        __syncthreads();
        for (int kk = 0; kk < kc; ++kk) {
            float wv = W[(long)(k0 + kk) * N + n0 + n_l];
#pragma unroll
            for (int bb = 0; bb < 8; ++bb) acc[bb] += As[(bh * 8 + bb) * 64 + kk] * wv;
        }
    }
    float bs = bias[n0 + n_l];
    for (int bb = 0; bb < 8; ++bb) {
        float x = acc[bb] + bs;
        float r;
        if (act == 0) r = x > 0.f ? x : 0.f;
        else r = 1.f / (1.f + __expf(-x));
        out[(long)(bch + bh * 8 + bb) * N + n0 + n_l] = r;
    }
}

extern "C" void kernel_launch(void* const* d_in, const int* in_sizes, int n_in,
                              void* d_out, int out_size, void* d_ws, size_t ws_size,
                              hipStream_t stream) {
    const float* x   = (const float*)d_in[0];
    const float* c1w = (const float*)d_in[1];
    const float* c1b = (const float*)d_in[2];
    const float* c2w = (const float*)d_in[3];
    const float* c2b = (const float*)d_in[4];
    const float* pw  = (const float*)d_in[5];
    const float* pb  = (const float*)d_in[6];
    const float* Wd  = (const float*)d_in[7];
    const float* bd  = (const float*)d_in[8];
    const float* rw1 = (const float*)d_in[9];
    const float* rb1 = (const float*)d_in[10];
    const float* rw2 = (const float*)d_in[11];
    const float* rb2 = (const float*)d_in[12];
    const float* rw3 = (const float*)d_in[13];
    const float* rb3 = (const float*)d_in[14];
    float* outp = (float*)d_out;

    char* ws = (char*)d_ws;
    size_t off = 0;
    auto alloc = [&](size_t bytes) {
        char* p = ws + off;
        off += (bytes + 255) & ~(size_t)255;
        return p;
    };
    __hip_bfloat16* c1out = (__hip_bfloat16*)alloc(150994944UL);  // [128][48][48][256] bf16
    __hip_bfloat16* c2out = (__hip_bfloat16*)alloc(26214400UL);   // [128][20][20][256]
    __hip_bfloat16* c3out = (__hip_bfloat16*)alloc(2359296UL);    // [128][6][6][256]
    __hip_bfloat16* w2p   = (__hip_bfloat16*)alloc(10616832UL);
    __hip_bfloat16* w3p   = (__hip_bfloat16*)alloc(10616832UL);
    float* u     = (float*)alloc(4718592UL);    // [128][1152][8] f32
    __hip_bfloat16* uhat = (__hip_bfloat16*)alloc(47185920UL);  // [128][10][1152][16] bf16
    float* vws   = (float*)alloc(81920UL);      // [128][160]
    float* rec1  = (float*)alloc(262144UL);     // [128][512]
    float* rec2  = (float*)alloc(524288UL);     // [128][1024]

    // conv3 split-K partials [9][4608][256] f32 = 42.5MB alias the (later-written) uhat buffer
    float* c3part = (float*)uhat;

    prep_w_kernel<<<512, 256, 0, stream>>>(c2w, w2p);
    prep_w_kernel<<<512, 256, 0, stream>>>(pw, w3p);
    conv1_kernel<<<dim3(48, 128), 256, 0, stream>>>(x, c1w, c1b, c1out);
    conv_mfma256_kernel<<<200, 512, 0, stream>>>(c1out, w2p, c2b, c2out,
                                                 48, 48 * 48 * 256, 400, 20, 200);
    conv_mfma_kernel<<<dim3(36, 2, 9), 256, 0, stream>>>(c2out, w3p, pb, c3out, c3part,
                                                         20, 20 * 20 * 256, 36, 6, 9, 4608, 1);
    reduce_parts_kernel<<<4608, 256, 0, stream>>>(c3part, pb, c3out);
    squash_caps_kernel<<<576, 256, 0, stream>>>(c3out, u);
    uhat_kernel<<<1152, 256, 0, stream>>>(u, Wd, uhat);
    routing_kernel<<<1280, 256, 0, stream>>>(uhat, bd, outp, vws);
    rec_gemm_kernel<<<dim3(8, 4), 256, 0, stream>>>(vws, rw1, rb1, rec1, 160, 512, 0);
    rec_gemm_kernel<<<dim3(16, 4), 256, 0, stream>>>(rec1, rw2, rb2, rec2, 512, 1024, 0);
    rec_gemm_kernel<<<dim3(49, 4), 256, 0, stream>>>(rec2, rw3, rb3, outp + 20480, 1024, 3136, 1);
}